// Round 8
// baseline (126.325 us; speedup 1.0000x reference)
//
#include <hip/hip_runtime.h>
#include <hip/hip_bf16.h>
#include <stdint.h>

// Problem constants: B=4, L=2048, D=1024, vocab<32, N_GRAM=3
#define LSEQ 2048
#define DDIM 1024

typedef __attribute__((ext_vector_type(8))) short bf16x8;
typedef __attribute__((ext_vector_type(16))) float f32x16;

__device__ __forceinline__ ushort f2bf(float x) {
    uint32_t u = __builtin_bit_cast(uint32_t, x);
    u += 0x7fffu + ((u >> 16) & 1u);   // RNE (inputs finite/normal)
    return (ushort)(u >> 16);
}

__device__ __forceinline__ void stage16(const void* g, void* lds) {
    __builtin_amdgcn_global_load_lds((const __attribute__((address_space(1))) void*)g,
                                     (__attribute__((address_space(3))) void*)lds, 16, 0, 0);
}

// Swizzled byte offset in a row-major bf16 buffer, 2048B row stride.
// Within each 128B k-block, 16B slot index XORed with (row&7). Baked into global
// layout by producers (rule 21) so global_load_lds copies linearly; readers XOR.
__device__ __forceinline__ int swz_off(int row, int k) {
    return row * 2048 + ((k >> 6) << 7) + ((((k >> 3) & 7) ^ (row & 7)) << 4) + ((k & 7) << 1);
}

__device__ __forceinline__ int key_at(const int* __restrict__ ids, int base, int j) {
    return j >= 2 ? ((ids[base + j - 2] << 10) | (ids[base + j - 1] << 5) | ids[base + j]) : 0;
}

// ---------------- Kernel 1 (fused prep): pooled (blocks 0..8191) + W-transpose ----
__global__ __launch_bounds__(256) void prep(const float* __restrict__ H,
                                            const int* __restrict__ ids,
                                            const float* __restrict__ W1,
                                            const float* __restrict__ W2,
                                            char* __restrict__ Pb,
                                            char* __restrict__ W1t,
                                            char* __restrict__ W2t) {
    int bid = blockIdx.x;
    int tid = threadIdx.x;
    if (bid < 8192) {
        // pooled[b,i,:] = mean_{j<i, ngram match} H[b,j,:]; deterministic bitmap scan
        int row = bid;
        int i = row & (LSEQ - 1);
        int base = row - i;
        int key_i = key_at(ids, base, i);
        const float4* H4 = (const float4*)H;

        __shared__ unsigned bm[8];
        float4 acc = make_float4(0.f, 0.f, 0.f, 0.f);
        int count = 0;
        for (int j0 = 0; j0 < i; j0 += 256) {
            if (tid < 8) bm[tid] = 0u;
            __syncthreads();
            int j = j0 + tid;
            if (j < i && key_at(ids, base, j) == key_i)
                atomicOr(&bm[tid >> 5], 1u << (tid & 31));
            __syncthreads();
            #pragma unroll
            for (int w = 0; w < 8; ++w) {
                unsigned m = bm[w];
                while (m) {
                    int bit = __ffs(m) - 1;
                    m &= m - 1;
                    int j2 = j0 + w * 32 + bit;
                    count++;
                    float4 h = H4[(size_t)(base + j2) * (DDIM / 4) + tid];
                    acc.x += h.x; acc.y += h.y; acc.z += h.z; acc.w += h.w;
                }
            }
            __syncthreads();
        }
        float s = 1.0f / (float)(count > 0 ? count : 1);
        ushort4 o;
        o.x = f2bf(acc.x * s); o.y = f2bf(acc.y * s);
        o.z = f2bf(acc.z * s); o.w = f2bf(acc.w * s);
        *(ushort4*)(Pb + swz_off(row, tid * 4)) = o;
    } else {
        // W[K][N] fp32 -> Wt[N][K] bf16, swizzle-baked. 512 blocks: 16(k) x 16(n) x 2
        int b2 = bid - 8192;
        const float* W = (b2 >> 8) ? W2 : W1;
        char* Wt = (b2 >> 8) ? W2t : W1t;
        int r2 = b2 & 255;
        int k0 = (r2 & 15) * 64, n0 = (r2 >> 4) * 64;
        __shared__ ushort t[64][65];
        #pragma unroll
        for (int it = 0; it < 16; ++it) {
            int idx = it * 256 + tid;
            int r = idx >> 6, c = idx & 63;
            t[c][r] = f2bf(W[(size_t)(k0 + r) * DDIM + n0 + c]);
        }
        __syncthreads();
        #pragma unroll
        for (int it = 0; it < 4; ++it) {
            int idx = it * 256 + tid;
            int r = idx >> 4, g = idx & 15;
            ushort4 v;
            v.x = t[r][g * 4]; v.y = t[r][g * 4 + 1];
            v.z = t[r][g * 4 + 2]; v.w = t[r][g * 4 + 3];
            *(ushort4*)(Wt + swz_off(n0 + r, k0 + g * 4)) = v;
        }
    }
}

// ---------------- Kernel 2: out = H@W1 + P@W2 + (b1+b2), 32x32x16 bf16 MFMA -------
// TLP round: tile 128(M)x64(N), 4 waves (2x2, wave tile 64x32), BK=64, grid 1024
// (= 4 blocks/CU dispatched, ~3 co-resident at launch_bounds(256,3)). SINGLE-
// buffered LDS (24KB), plain m97 2-barrier loop, NO manual waitcnt — latency is
// hidden by inter-block TLP (m114/m102: 320 TF @1blk/CU -> 833 TF @3blk/CU).
// XCD mapping: xcd=bid&7 owns a 1024-row slab x all 16 col-tiles (L2-resident).
__global__ __launch_bounds__(256, 3) void gemm_bf16(
    const float* __restrict__ H,      // [8192][1024] fp32 (converted in-flight)
    const char* __restrict__ Pb,      // [8192][1024] bf16, swizzle-baked
    const char* __restrict__ W1t,     // [1024 n][1024 k] bf16, swizzle-baked
    const char* __restrict__ W2t,
    const float* __restrict__ b1,
    const float* __restrict__ b2,
    float* __restrict__ out)          // [8192][1024] fp32
{
    __shared__ __align__(128) char As[128 * 128];   // 16KB: [128 rows][128B = 64 bf16]
    __shared__ __align__(128) char Bs[64 * 128];    // 8KB

    const int tid = threadIdx.x;      // 0..255
    const int lane = tid & 63;
    const int wid = tid >> 6;         // 0..3
    const int wr = wid >> 1, wc = wid & 1;
    const int l31 = lane & 31;
    const int hi2 = lane >> 5;
    const int x7 = l31 & 7;

    // XCD mapping: bid = xcd + 8*j; xcd owns M-rows [xcd*1024, +1024) x all cols
    const int bid = blockIdx.x;
    const int j = bid >> 3;                               // 0..127
    const int row0 = ((bid & 7) * 8 + (j & 7)) * 128;     // 64 M-tiles of 128
    const int col0 = (j >> 3) * 64;                       // 16 N-tiles of 64

    f32x16 acc[2];
    #pragma unroll
    for (int mm = 0; mm < 2; ++mm)
        #pragma unroll
        for (int q = 0; q < 16; ++q) acc[mm][q] = 0.f;

    // glds staging geometry: one 4KB issue = 32 rows of 128B
    const int o_lin = wid * 1024 + lane * 16;
    const int srow = o_lin >> 7;        // 0..31
    const int sbyte = o_lin & 127;

    // H reg-stage: thread owns row tid>>1, 64B half tid&1 of the 128B LDS row
    const int hrow = tid >> 1;          // 0..127
    const int hhalf = tid & 1;
    const float* Hrow = H + (size_t)(row0 + hrow) * DDIM + hhalf * 32;
    const int hx = hrow & 7;

    const char* Arow0 = As + (wr * 64 + l31) * 128;   // + mm*32*128 for frag mm
    const char* Brow  = Bs + (wc * 32 + l31) * 128;

    #pragma unroll 1
    for (int t = 0; t < 32; ++t) {
        // ---- stage K-step t into the single buffer ----
        if (t < 16) {
            // H-path: per-lane fp32 loads first, then B glds (hv waits leave glds in flight)
            const float* hs = Hrow + t * 64;
            float4 hv[8];
            #pragma unroll
            for (int q = 0; q < 8; ++q) hv[q] = *(const float4*)(hs + q * 4);
            #pragma unroll
            for (int c = 0; c < 2; ++c)
                stage16(W1t + (size_t)(col0 + c * 32 + srow) * 2048 + (t << 7) + sbyte,
                        Bs + c * 4096 + wid * 1024);
            #pragma unroll
            for (int q = 0; q < 4; ++q) {
                union { ushort u[8]; int4 v; } p;
                float4 a = hv[2 * q], b = hv[2 * q + 1];
                p.u[0] = f2bf(a.x); p.u[1] = f2bf(a.y); p.u[2] = f2bf(a.z); p.u[3] = f2bf(a.w);
                p.u[4] = f2bf(b.x); p.u[5] = f2bf(b.y); p.u[6] = f2bf(b.z); p.u[7] = f2bf(b.w);
                int slot = (hhalf * 4 + q) ^ hx;
                *(int4*)(As + hrow * 128 + slot * 16) = p.v;   // swizzle baked at write
            }
        } else {
            int kb = (t - 16) << 7;
            #pragma unroll
            for (int c = 0; c < 4; ++c)
                stage16(Pb + (size_t)(row0 + c * 32 + srow) * 2048 + kb + sbyte,
                        As + c * 4096 + wid * 1024);
            #pragma unroll
            for (int c = 0; c < 2; ++c)
                stage16(W2t + (size_t)(col0 + c * 32 + srow) * 2048 + kb + sbyte,
                        Bs + c * 4096 + wid * 1024);
        }
        __syncthreads();   // compiler drains vmcnt+lgkmcnt; publishes buffer

        // ---- compute K-step t ----
        bf16x8 bfr[4], af0[4], af1[4];
        #pragma unroll
        for (int ks = 0; ks < 4; ++ks) {
            const int so = ((ks * 2 + hi2) ^ x7) << 4;
            bfr[ks] = *(const bf16x8*)(Brow + so);
            af0[ks] = *(const bf16x8*)(Arow0 + so);
            af1[ks] = *(const bf16x8*)(Arow0 + 32 * 128 + so);
        }
        __builtin_amdgcn_s_setprio(1);
        #pragma unroll
        for (int ks = 0; ks < 4; ++ks)
            acc[0] = __builtin_amdgcn_mfma_f32_32x32x16_bf16(af0[ks], bfr[ks], acc[0], 0, 0, 0);
        #pragma unroll
        for (int ks = 0; ks < 4; ++ks)
            acc[1] = __builtin_amdgcn_mfma_f32_32x32x16_bf16(af1[ks], bfr[ks], acc[1], 0, 0, 0);
        __builtin_amdgcn_s_setprio(0);
        __syncthreads();   // all waves done reading; safe to overwrite next iter
    }

    // epilogue: 32x32 C/D layout col=lane&31, row=(reg&3)+8*(reg>>2)+4*(lane>>5)
    {
        const int c = col0 + wc * 32 + l31;
        const float bias = b1[c] + b2[c];
        #pragma unroll
        for (int mm = 0; mm < 2; ++mm) {
            const int rbase = row0 + wr * 64 + mm * 32 + hi2 * 4;
            #pragma unroll
            for (int reg = 0; reg < 16; ++reg) {
                int r = rbase + (reg & 3) + 8 * (reg >> 2);
                out[(size_t)r * DDIM + c] = acc[mm][reg] + bias;
            }
        }
    }
}

extern "C" void kernel_launch(void* const* d_in, const int* in_sizes, int n_in,
                              void* d_out, int out_size, void* d_ws, size_t ws_size,
                              hipStream_t stream) {
    const float* H  = (const float*)d_in[0];
    const int*   ids = (const int*)d_in[1];
    const float* W1 = (const float*)d_in[2];
    const float* b1 = (const float*)d_in[3];
    const float* W2 = (const float*)d_in[4];
    const float* b2 = (const float*)d_in[5];
    float* out = (float*)d_out;

    char* ws = (char*)d_ws;
    char* Pb  = ws;                      // 16MB bf16 pooled (swizzle-baked)
    char* W1t = ws + (16 << 20);         // 2MB
    char* W2t = ws + (18 << 20);         // 2MB  (total 20MB, proven-safe)

    prep<<<8192 + 512, 256, 0, stream>>>(H, ids, W1, W2, Pb, W1t, W2t);
    gemm_bf16<<<1024, 256, 0, stream>>>(H, Pb, W1t, W2t, b1, b2, out);
}

// Round 9
// 81.497 us; speedup vs baseline: 1.5501x; 1.5501x over previous
//
#include <hip/hip_runtime.h>
#include <hip/hip_bf16.h>
#include <stdint.h>

// Problem constants: B=4, L=2048, D=1024, vocab<32, N_GRAM=3
#define LSEQ 2048
#define DDIM 1024

typedef __attribute__((ext_vector_type(8))) short bf16x8;
typedef __attribute__((ext_vector_type(16))) float f32x16;

__device__ __forceinline__ ushort f2bf(float x) {
    uint32_t u = __builtin_bit_cast(uint32_t, x);
    u += 0x7fffu + ((u >> 16) & 1u);   // RNE (inputs finite/normal)
    return (ushort)(u >> 16);
}

__device__ __forceinline__ void stage16(const void* g, void* lds) {
    __builtin_amdgcn_global_load_lds((const __attribute__((address_space(1))) void*)g,
                                     (__attribute__((address_space(3))) void*)lds, 16, 0, 0);
}

// Swizzled byte offset in a row-major bf16 buffer, 2048B row stride.
// Within each 128B k-block, 16B slot index XORed with (row&7). Baked into global
// layout by producers (rule 21) so global_load_lds copies linearly; readers XOR.
__device__ __forceinline__ int swz_off(int row, int k) {
    return row * 2048 + ((k >> 6) << 7) + ((((k >> 3) & 7) ^ (row & 7)) << 4) + ((k & 7) << 1);
}

__device__ __forceinline__ int key_at(const int* __restrict__ ids, int base, int j) {
    return j >= 2 ? ((ids[base + j - 2] << 10) | (ids[base + j - 1] << 5) | ids[base + j]) : 0;
}

// ------- Kernel 1 (fused prep): pooled + W-transpose + (primary) H->bf16 ---------
// blocks [0,8192): pooled rows; [8192,8704): W tiles; [8704,9728): H conversion.
__global__ __launch_bounds__(256) void prep(const float* __restrict__ H,
                                            const int* __restrict__ ids,
                                            const float* __restrict__ W1,
                                            const float* __restrict__ W2,
                                            char* __restrict__ Hb,
                                            char* __restrict__ Pb,
                                            char* __restrict__ W1t,
                                            char* __restrict__ W2t) {
    int bid = blockIdx.x;
    int tid = threadIdx.x;
    if (bid < 8192) {
        // pooled[b,i,:] = mean_{j<i, ngram match} H[b,j,:]; deterministic bitmap scan
        int row = bid;
        int i = row & (LSEQ - 1);
        int base = row - i;
        int key_i = key_at(ids, base, i);
        const float4* H4 = (const float4*)H;

        __shared__ unsigned bm[8];
        float4 acc = make_float4(0.f, 0.f, 0.f, 0.f);
        int count = 0;
        for (int j0 = 0; j0 < i; j0 += 256) {
            if (tid < 8) bm[tid] = 0u;
            __syncthreads();
            int j = j0 + tid;
            if (j < i && key_at(ids, base, j) == key_i)
                atomicOr(&bm[tid >> 5], 1u << (tid & 31));
            __syncthreads();
            #pragma unroll
            for (int w = 0; w < 8; ++w) {
                unsigned m = bm[w];
                while (m) {
                    int bit = __ffs(m) - 1;
                    m &= m - 1;
                    int j2 = j0 + w * 32 + bit;
                    count++;
                    float4 h = H4[(size_t)(base + j2) * (DDIM / 4) + tid];
                    acc.x += h.x; acc.y += h.y; acc.z += h.z; acc.w += h.w;
                }
            }
            __syncthreads();
        }
        float s = 1.0f / (float)(count > 0 ? count : 1);
        ushort4 o;
        o.x = f2bf(acc.x * s); o.y = f2bf(acc.y * s);
        o.z = f2bf(acc.z * s); o.w = f2bf(acc.w * s);
        *(ushort4*)(Pb + swz_off(row, tid * 4)) = o;
    } else if (bid < 8704) {
        // W[K][N] fp32 -> Wt[N][K] bf16, swizzle-baked. 512 blocks: 16(k) x 16(n) x 2
        int b2 = bid - 8192;
        const float* W = (b2 >> 8) ? W2 : W1;
        char* Wt = (b2 >> 8) ? W2t : W1t;
        int r2 = b2 & 255;
        int k0 = (r2 & 15) * 64, n0 = (r2 >> 4) * 64;
        __shared__ ushort t[64][65];
        #pragma unroll
        for (int it = 0; it < 16; ++it) {
            int idx = it * 256 + tid;
            int r = idx >> 6, c = idx & 63;
            t[c][r] = f2bf(W[(size_t)(k0 + r) * DDIM + n0 + c]);
        }
        __syncthreads();
        #pragma unroll
        for (int it = 0; it < 4; ++it) {
            int idx = it * 256 + tid;
            int r = idx >> 4, g = idx & 15;
            ushort4 v;
            v.x = t[r][g * 4]; v.y = t[r][g * 4 + 1];
            v.z = t[r][g * 4 + 2]; v.w = t[r][g * 4 + 3];
            *(ushort4*)(Wt + swz_off(n0 + r, k0 + g * 4)) = v;
        }
    } else {
        // H fp32 -> Hb bf16, swizzle-baked (primary mode only). 1024 blocks x 8 rows.
        int r0 = (bid - 8704) * 8;
        #pragma unroll
        for (int rr = 0; rr < 8; ++rr) {
            int row = r0 + rr;
            float4 h = *(const float4*)(H + (size_t)row * DDIM + tid * 4);
            ushort4 o;
            o.x = f2bf(h.x); o.y = f2bf(h.y); o.z = f2bf(h.z); o.w = f2bf(h.w);
            *(ushort4*)(Hb + swz_off(row, tid * 4)) = o;
        }
    }
}

// ---------------- Kernel 2: out = H@W1 + P@W2 + (b1+b2), 32x32x16 bf16 MFMA -------
// Tile 256(M)x128(N), BK=64, 8 waves (4Mx2N), wave tile 64x64. Grid 256 = 1/CU.
// Triple-buffered LDS, depth-2 prefetch, counted vmcnt (never 0 in-loop).
// HB=true (primary): UNIFORM loop — all four operands via global_load_lds from
//   bf16 swizzle-baked buffers (Hb steps 0-15, Pb 16-31). Zero VALU cvt, no ds_write.
// HB=false (fallback, small ws): R5 dataflow, H reg-converted via v_cvt_pk_bf16_f32.
template<bool HBMODE>
__global__ __launch_bounds__(512, 2) void gemm_bf16(
    const float* __restrict__ H,
    const char* __restrict__ Hb,      // bf16 swizzle-baked (primary only)
    const char* __restrict__ Pb,
    const char* __restrict__ W1t,
    const char* __restrict__ W2t,
    const float* __restrict__ b1,
    const float* __restrict__ b2,
    float* __restrict__ out)
{
    __shared__ __align__(128) char AsBuf[3][32768];   // [256 rows][128B]
    __shared__ __align__(128) char BsBuf[3][16384];   // [128 rows][128B]

    const int tid = threadIdx.x;
    const int lane = tid & 63;
    const int wid = tid >> 6;
    const int wr = wid >> 1, wc = wid & 1;
    const int l31 = lane & 31;
    const int hi2 = lane >> 5;
    const int x7 = l31 & 7;

    // XCD-aware mapping (R5-proven, FETCH-optimal): xcd owns 4 row-tiles x 8 col-tiles
    const int bid = blockIdx.x;
    const int j = bid >> 3;
    const int row0 = ((bid & 7) * 4 + (j >> 3)) * 256;
    const int col0 = (j & 7) * 128;

    f32x16 acc[2][2];
    #pragma unroll
    for (int mm = 0; mm < 2; ++mm)
        #pragma unroll
        for (int nn = 0; nn < 2; ++nn)
            #pragma unroll
            for (int q = 0; q < 16; ++q) acc[mm][nn][q] = 0.f;

    const int o_lin = wid * 1024 + lane * 16;
    const int srow = o_lin >> 7;
    const int sbyte = o_lin & 127;

    const int hrow = tid >> 1;
    const int hhalf = tid & 1;
    const float* Hrow = H + (size_t)(row0 + hrow) * DDIM + hhalf * 32;
    const int hx = hrow & 7;

    char* Acur = &AsBuf[0][0]; char* Anx1 = &AsBuf[1][0]; char* Anx2 = &AsBuf[2][0];
    char* Bcur = &BsBuf[0][0]; char* Bnx1 = &BsBuf[1][0]; char* Bnx2 = &BsBuf[2][0];

    auto stageB = [&](char* dstB, const char* W, int kb) {
        #pragma unroll
        for (int c = 0; c < 2; ++c)
            stage16(W + (size_t)(col0 + c * 64 + srow) * 2048 + kb + sbyte,
                    dstB + c * 8192 + wid * 1024);
    };
    auto stageA = [&](char* dstA, const char* Ab, int kb) {
        #pragma unroll
        for (int c = 0; c < 4; ++c)
            stage16(Ab + (size_t)(row0 + c * 64 + srow) * 2048 + kb + sbyte,
                    dstA + c * 8192 + wid * 1024);
    };
    auto loadH = [&](float4* hv, int t) {
        const float* hs = Hrow + t * 64;
        #pragma unroll
        for (int q = 0; q < 8; ++q) hv[q] = *(const float4*)(hs + q * 4);
    };
    auto writeH = [&](char* dstA, const float4* hv) {
        #pragma unroll
        for (int q = 0; q < 4; ++q) {
            float4 a = hv[2 * q], b = hv[2 * q + 1];
            uint32_t w0, w1, w2, w3;
            asm("v_cvt_pk_bf16_f32 %0, %1, %2" : "=v"(w0) : "v"(a.x), "v"(a.y));
            asm("v_cvt_pk_bf16_f32 %0, %1, %2" : "=v"(w1) : "v"(a.z), "v"(a.w));
            asm("v_cvt_pk_bf16_f32 %0, %1, %2" : "=v"(w2) : "v"(b.x), "v"(b.y));
            asm("v_cvt_pk_bf16_f32 %0, %1, %2" : "=v"(w3) : "v"(b.z), "v"(b.w));
            int4 v = make_int4(w0, w1, w2, w3);
            int slot = (hhalf * 4 + q) ^ hx;
            *(int4*)(dstA + hrow * 128 + slot * 16) = v;
        }
    };
    auto compute = [&]() {
        bf16x8 af[2][4], bf[2][4];
        #pragma unroll
        for (int ks = 0; ks < 4; ++ks) {
            const int so = ((ks * 2 + hi2) ^ x7) << 4;
            #pragma unroll
            for (int mm = 0; mm < 2; ++mm)
                af[mm][ks] = *(const bf16x8*)(Acur + (wr * 64 + mm * 32 + l31) * 128 + so);
            #pragma unroll
            for (int nn = 0; nn < 2; ++nn)
                bf[nn][ks] = *(const bf16x8*)(Bcur + (wc * 64 + nn * 32 + l31) * 128 + so);
        }
        __builtin_amdgcn_s_setprio(1);
        #pragma unroll
        for (int ks = 0; ks < 4; ++ks)
            #pragma unroll
            for (int mm = 0; mm < 2; ++mm)
                #pragma unroll
                for (int nn = 0; nn < 2; ++nn)
                    acc[mm][nn] = __builtin_amdgcn_mfma_f32_32x32x16_bf16(
                        af[mm][ks], bf[nn][ks], acc[mm][nn], 0, 0, 0);
        __builtin_amdgcn_s_setprio(0);
    };
    auto rotate = [&]() {
        char* tp;
        tp = Acur; Acur = Anx1; Anx1 = Anx2; Anx2 = tp;
        tp = Bcur; Bcur = Bnx1; Bnx1 = Bnx2; Bnx2 = tp;
    };

    if constexpr (HBMODE) {
        // -------- primary: uniform all-glds loop --------
        stageA(Acur, Hb, 0);        stageB(Bcur, W1t, 0);
        stageA(Anx1, Hb, 1 << 7);   stageB(Bnx1, W1t, 1 << 7);
        asm volatile("s_waitcnt vmcnt(6)" ::: "memory");    // tile 0 staged
        __builtin_amdgcn_s_barrier();

        #pragma unroll 1
        for (int t = 0; t < 30; ++t) {
            const int t2 = t + 2;
            const char* Ab = t2 < 16 ? Hb : Pb;
            const char* Wb = t2 < 16 ? W1t : W2t;
            const int kb = (t2 & 15) << 7;
            stageA(Anx2, Ab, kb);
            stageB(Bnx2, Wb, kb);
            compute();
            asm volatile("s_waitcnt vmcnt(6)" ::: "memory");  // t+1 staged; t+2 in flight
            __builtin_amdgcn_s_barrier();
            rotate();
        }
        compute();
        asm volatile("s_waitcnt vmcnt(0)" ::: "memory");
        __builtin_amdgcn_s_barrier();
        rotate();
        compute();
    } else {
        // -------- fallback (small ws): R5 dataflow + cvt_pk H conversion --------
        float4 hvA[8], hvB[8];
        stageB(Bcur, W1t, 0);        loadH(hvA, 0);
        stageB(Bnx1, W1t, 1 << 7);   loadH(hvB, 1);
        asm volatile("s_waitcnt vmcnt(10)" ::: "memory");
        writeH(Acur, hvA);
        asm volatile("s_waitcnt lgkmcnt(0)" ::: "memory");
        __builtin_amdgcn_s_barrier();

        #pragma unroll 1
        for (int t = 0; t < 14; t += 2) {
            stageB(Bnx2, W1t, (t + 2) << 7);
            loadH(hvA, t + 2);
            compute();
            asm volatile("s_waitcnt vmcnt(10)" ::: "memory");
            writeH(Anx1, hvB);
            asm volatile("s_waitcnt lgkmcnt(0)" ::: "memory");
            __builtin_amdgcn_s_barrier();
            rotate();
            stageB(Bnx2, W1t, (t + 3) << 7);
            loadH(hvB, t + 3);
            compute();
            asm volatile("s_waitcnt vmcnt(10)" ::: "memory");
            writeH(Anx1, hvA);
            asm volatile("s_waitcnt lgkmcnt(0)" ::: "memory");
            __builtin_amdgcn_s_barrier();
            rotate();
        }
        // iter 14: stage P-tile 16; publish A(15)=hvB
        stageA(Anx2, Pb, 0); stageB(Bnx2, W2t, 0);
        compute();
        asm volatile("s_waitcnt vmcnt(6)" ::: "memory");
        writeH(Anx1, hvB);
        asm volatile("s_waitcnt lgkmcnt(0)" ::: "memory");
        __builtin_amdgcn_s_barrier();
        rotate();
        // iter 15 .. 29
        #pragma unroll 1
        for (int t = 15; t < 30; ++t) {
            int kb = (t - 14) << 7;
            stageA(Anx2, Pb, kb); stageB(Bnx2, W2t, kb);
            compute();
            asm volatile("s_waitcnt vmcnt(6)" ::: "memory");
            __builtin_amdgcn_s_barrier();
            rotate();
        }
        compute();
        asm volatile("s_waitcnt vmcnt(0)" ::: "memory");
        __builtin_amdgcn_s_barrier();
        rotate();
        compute();
    }

    // epilogue: 32x32 C/D layout col=lane&31, row=(reg&3)+8*(reg>>2)+4*(lane>>5)
    #pragma unroll
    for (int mm = 0; mm < 2; ++mm) {
        #pragma unroll
        for (int nn = 0; nn < 2; ++nn) {
            const int c = col0 + wc * 64 + nn * 32 + l31;
            const float bias = b1[c] + b2[c];
            const int rbase = row0 + wr * 64 + mm * 32 + hi2 * 4;
            #pragma unroll
            for (int reg = 0; reg < 16; ++reg) {
                int r = rbase + (reg & 3) + 8 * (reg >> 2);
                out[(size_t)r * DDIM + c] = acc[mm][nn][reg] + bias;
            }
        }
    }
}

extern "C" void kernel_launch(void* const* d_in, const int* in_sizes, int n_in,
                              void* d_out, int out_size, void* d_ws, size_t ws_size,
                              hipStream_t stream) {
    const float* H  = (const float*)d_in[0];
    const int*   ids = (const int*)d_in[1];
    const float* W1 = (const float*)d_in[2];
    const float* b1 = (const float*)d_in[3];
    const float* W2 = (const float*)d_in[4];
    const float* b2 = (const float*)d_in[5];
    float* out = (float*)d_out;

    char* ws = (char*)d_ws;
    const bool big = ws_size >= (size_t)(36u << 20);

    if (big) {
        // primary: Hb 16MB | Pb 16MB | W1t 2MB | W2t 2MB = 36MB
        char* Hb  = ws;
        char* Pb  = ws + (16 << 20);
        char* W1t = ws + (32 << 20);
        char* W2t = ws + (34 << 20);
        prep<<<9728, 256, 0, stream>>>(H, ids, W1, W2, Hb, Pb, W1t, W2t);
        gemm_bf16<true><<<256, 512, 0, stream>>>(H, Hb, Pb, W1t, W2t, b1, b2, out);
    } else {
        // fallback: Pb 16MB | W1t 2MB | W2t 2MB = 20MB (proven-safe)
        char* Pb  = ws;
        char* W1t = ws + (16 << 20);
        char* W2t = ws + (18 << 20);
        prep<<<8704, 256, 0, stream>>>(H, ids, W1, W2, nullptr, Pb, W1t, W2t);
        gemm_bf16<false><<<256, 512, 0, stream>>>(H, nullptr, Pb, W1t, W2t, b1, b2, out);
    }
}